// Round 7
// baseline (263.747 us; speedup 1.0000x reference)
//
#include <hip/hip_runtime.h>
#include <hip/hip_bf16.h>
#include <math.h>

typedef float f32x4 __attribute__((ext_vector_type(4)));
typedef short s16x8 __attribute__((ext_vector_type(8)));
typedef unsigned short us16x4 __attribute__((ext_vector_type(4)));
typedef unsigned short us16x8 __attribute__((ext_vector_type(8)));
typedef unsigned int u32x2 __attribute__((ext_vector_type(2)));

#define MFMA16(a, b, c) __builtin_amdgcn_mfma_f32_16x16x32_bf16(a, b, c, 0, 0, 0)

static constexpr int B_ = 2, S_ = 2048, D_ = 1024, H_ = 16, HD_ = 64;
// Q pre-scale: HD^-0.5 * log2(e)  -> flash softmax in exp2 domain, no max needed
static constexpr float QSCALE = 0.125f * 1.44269504088896340736f;

__device__ __forceinline__ unsigned short f2bf(float f) {
    unsigned int u = __builtin_bit_cast(unsigned int, f);
    u += 0x7fffu + ((u >> 16) & 1);  // round-to-nearest-even
    return (unsigned short)(u >> 16);
}

// packed fp32x2 -> bf16x2 (lo=a, hi=b), RNE. HW inst on gfx950.
#if defined(__has_builtin) && __has_builtin(__builtin_amdgcn_cvt_pk_bf16_f32)
typedef __bf16 bf16x2v __attribute__((ext_vector_type(2)));
__device__ __forceinline__ unsigned int pk_bf16(float a, float b) {
    return __builtin_bit_cast(unsigned int, __builtin_amdgcn_cvt_pk_bf16_f32(a, b));
}
#else
__device__ __forceinline__ unsigned int pk_bf16(float a, float b) {
    return ((unsigned int)f2bf(a)) | (((unsigned int)f2bf(b)) << 16);
}
#endif

__device__ __forceinline__ void glds16(const unsigned short* g, unsigned short* l) {
    __builtin_amdgcn_global_load_lds(
        (const __attribute__((address_space(1))) void*)g,
        (__attribute__((address_space(3))) void*)l, 16, 0, 0);
}

// ---------------------------------------------------------------------------
// fp32 -> bf16 flat converts
// ---------------------------------------------------------------------------
__global__ __launch_bounds__(256) void conv3(const float* __restrict__ s0,
                                             const float* __restrict__ s1,
                                             const float* __restrict__ s2,
                                             unsigned short* __restrict__ d0,
                                             unsigned short* __restrict__ d1,
                                             unsigned short* __restrict__ d2) {
    const int z = blockIdx.z;
    const float* src = (z == 0) ? s0 : (z == 1) ? s1 : s2;
    unsigned short* dst = (z == 0) ? d0 : (z == 1) ? d1 : d2;
    int i = (blockIdx.x * 256 + threadIdx.x) * 8;
    f32x4 a = *(const f32x4*)&src[i];
    f32x4 b = *(const f32x4*)&src[i + 4];
    s16x8 o;
#pragma unroll
    for (int j = 0; j < 4; j++) { o[j] = (short)f2bf(a[j]); o[4 + j] = (short)f2bf(b[j]); }
    *(s16x8*)&dst[i] = o;
}

__global__ __launch_bounds__(256) void conv_bf16(const float* __restrict__ src,
                                                 unsigned short* __restrict__ dst) {
    int i = (blockIdx.x * 256 + threadIdx.x) * 8;
    f32x4 a = *(const f32x4*)&src[i];
    f32x4 b = *(const f32x4*)&src[i + 4];
    s16x8 o;
#pragma unroll
    for (int j = 0; j < 4; j++) { o[j] = (short)f2bf(a[j]); o[4 + j] = (short)f2bf(b[j]); }
    *(s16x8*)&dst[i] = o;
}

// ---------------------------------------------------------------------------
// Weight transpose: Wt[(h*64+e)*1024 + d] = W[h*65536 + d*64 + e]
// ---------------------------------------------------------------------------
__global__ __launch_bounds__(256) void transpose_w3(const float* __restrict__ W0,
                                                    const float* __restrict__ W1,
                                                    const float* __restrict__ W2,
                                                    unsigned short* __restrict__ Wt3) {
    const int z = blockIdx.z;
    const float* W = (z == 0) ? W0 : (z == 1) ? W1 : W2;
    unsigned short* dst = Wt3 + ((size_t)z << 20);
    const int h = blockIdx.x >> 2, dg = blockIdx.x & 3;
    const int lane = threadIdx.x & 63, w = threadIdx.x >> 6;
    const float* Wh = W + ((size_t)h << 16);
#pragma unroll
    for (int it = 0; it < 8; it++) {
        int d0 = dg * 256 + it * 32 + w * 8;
        us16x8 o;
#pragma unroll
        for (int j = 0; j < 8; j++) o[j] = f2bf(Wh[(d0 + j) * 64 + lane]);
        *(us16x8*)&dst[(size_t)(h * 64 + lane) * 1024 + d0] = o;
    }
}

// ---------------------------------------------------------------------------
// 128x128-tile bf16 GEMM core, K=1024, BK=64, global_load_lds, XOR swizzle.
// ---------------------------------------------------------------------------
__device__ __forceinline__ void gemm_core128(const unsigned short* __restrict__ A,
                                             const unsigned short* __restrict__ Bt,
                                             unsigned short* As, unsigned short* Bs,
                                             int m0, int n0, f32x4 acc[4][4]) {
    const int tid = threadIdx.x;
    const int lane = tid & 63;
    const int w = tid >> 6, wm = w & 1, wn = w >> 1;
    const int l16 = lane & 15, quad = lane >> 4;
    const int srow = tid >> 3;
    const int sg = (tid & 7) ^ (srow & 7);
    const unsigned short* Ag = A + (size_t)(m0 + srow) * 1024 + sg * 8;
    const unsigned short* Bg = Bt + (size_t)(n0 + srow) * 1024 + sg * 8;
    unsigned short* Al = As + tid * 8;
    unsigned short* Bl = Bs + tid * 8;
    const int xo = (l16 & 7);

    for (int k0 = 0; k0 < 1024; k0 += 64) {
        __syncthreads();
#pragma unroll
        for (int c = 0; c < 4; c++) {
            glds16(Ag + (size_t)c * 32 * 1024 + k0, Al + c * 2048);
            glds16(Bg + (size_t)c * 32 * 1024 + k0, Bl + c * 2048);
        }
        __syncthreads();
#pragma unroll
        for (int kc = 0; kc < 2; kc++) {
            s16x8 bf[4];
#pragma unroll
            for (int nt = 0; nt < 4; nt++)
                bf[nt] = *(const s16x8*)&Bs[(wn * 64 + nt * 16 + l16) * 64 +
                                            (((kc * 4 + quad) ^ xo) * 8)];
#pragma unroll
            for (int mt = 0; mt < 4; mt++) {
                s16x8 af = *(const s16x8*)&As[(wm * 64 + mt * 16 + l16) * 64 +
                                              (((kc * 4 + quad) ^ xo) * 8)];
#pragma unroll
                for (int nt = 0; nt < 4; nt++)
                    acc[mt][nt] = MFMA16(af, bf[nt], acc[mt][nt]);
            }
        }
    }
}

// QKV fused via grid.z: z=0 Q -> row-major [B,S,D] (pre-scaled), z=1 K -> row-major,
// z=2 V -> transposed [B,H,HD,S]. Epilogue: per-wave LDS transpose -> 16B stores.
__global__ __launch_bounds__(256) void gemm_qkv(const unsigned short* __restrict__ Qc,
                                                const unsigned short* __restrict__ Kc,
                                                const unsigned short* __restrict__ Vc,
                                                const unsigned short* __restrict__ Wt3,
                                                const float* __restrict__ bq,
                                                const float* __restrict__ bk,
                                                const float* __restrict__ bv,
                                                unsigned short* __restrict__ Qr,
                                                unsigned short* __restrict__ Kr,
                                                unsigned short* __restrict__ Vt) {
    __shared__ unsigned short As[128 * 64];
    __shared__ unsigned short Bs[128 * 64];
    const int z = blockIdx.z;
    const unsigned short* A = (z == 0) ? Qc : (z == 1) ? Kc : Vc;
    const unsigned short* Bt = Wt3 + ((size_t)z << 20);
    const float* bias = (z == 0) ? bq : (z == 1) ? bk : bv;
    const int m0 = blockIdx.y * 128, n0 = blockIdx.x * 128;

    f32x4 acc[4][4] = {};
    gemm_core128(A, Bt, As, Bs, m0, n0, acc);

    const int tid = threadIdx.x;
    const int lane = tid & 63, w = tid >> 6;
    const int wm = w & 1, wn = w >> 1;
    const int l16 = lane & 15, quad = lane >> 4;
    const float scl = (z == 0) ? QSCALE : 1.0f;

    __syncthreads();  // all waves done with K-loop LDS reads
    unsigned short* T = ((w < 2) ? As : Bs) + (w & 1) * 4096;  // per-wave 64x64
#pragma unroll
    for (int mt = 0; mt < 4; mt++)
#pragma unroll
        for (int nt = 0; nt < 4; nt++) {
            int nl = nt * 16 + l16;
            float bsv = bias[n0 + wn * 64 + nl];
#pragma unroll
            for (int r = 0; r < 4; r++) {
                int ml = mt * 16 + quad * 4 + r;
                unsigned short val = f2bf((acc[mt][nt][r] + bsv) * scl);
                int row = (z == 2) ? nl : ml;
                int col = (z == 2) ? ml : nl;
                T[row * 64 + (((col >> 3) ^ (row & 7)) * 8) + (col & 7)] = val;
            }
        }
    // same-wave RAW: compiler orders via lgkmcnt; per-wave private region
#pragma unroll
    for (int it = 0; it < 8; it++) {
        int rr = it * 8 + (lane >> 3);
        int g = lane & 7;
        us16x8 vv = *(const us16x8*)&T[rr * 64 + ((g ^ (rr & 7)) * 8)];
        if (z == 2) {
            int n = n0 + wn * 64 + rr;           // h*64+e
            int mb = m0 + wm * 64 + g * 8;
            int b = mb >> 11, s = mb & 2047;
            *(us16x8*)&Vt[(((size_t)(b * H_ + (n >> 6))) * HD_ + (n & 63)) * S_ + s] = vv;
        } else {
            unsigned short* dst = z ? Kr : Qr;
            *(us16x8*)&dst[(size_t)(m0 + wm * 64 + rr) * 1024 + n0 + wn * 64 + g * 8] = vv;
        }
    }
}

// ---------------------------------------------------------------------------
// Final: C_f32[4096][1024] = Cc * Wp^T + bp.  128x64 tile -> 512 blocks.
// ---------------------------------------------------------------------------
__global__ __launch_bounds__(256) void gemm_out(const unsigned short* __restrict__ A,
                                                const unsigned short* __restrict__ Bt,
                                                const float* __restrict__ bias,
                                                float* __restrict__ C) {
    __shared__ unsigned short As[128 * 64];   // 16 KB
    __shared__ unsigned short Bs[64 * 64];    // 8 KB
    const int tid = threadIdx.x;
    const int lane = tid & 63;
    const int w = tid >> 6, wm = w & 1, wn = w >> 1;  // wn 0..1
    const int l16 = lane & 15, quad = lane >> 4;
    const int m0 = blockIdx.y * 128, n0 = blockIdx.x * 64;
    const int srow = tid >> 3;
    const int sg = (tid & 7) ^ (srow & 7);
    const unsigned short* Ag = A + (size_t)(m0 + srow) * 1024 + sg * 8;
    const unsigned short* Bg = Bt + (size_t)(n0 + srow) * 1024 + sg * 8;
    unsigned short* Al = As + tid * 8;
    unsigned short* Bl = Bs + tid * 8;
    const int xo = l16 & 7;

    f32x4 acc[4][2] = {};
    for (int k0 = 0; k0 < 1024; k0 += 64) {
        __syncthreads();
#pragma unroll
        for (int c = 0; c < 4; c++)
            glds16(Ag + (size_t)c * 32 * 1024 + k0, Al + c * 2048);
#pragma unroll
        for (int c = 0; c < 2; c++)
            glds16(Bg + (size_t)c * 32 * 1024 + k0, Bl + c * 2048);
        __syncthreads();
#pragma unroll
        for (int kc = 0; kc < 2; kc++) {
            s16x8 bf[2];
#pragma unroll
            for (int nt = 0; nt < 2; nt++)
                bf[nt] = *(const s16x8*)&Bs[(wn * 32 + nt * 16 + l16) * 64 +
                                            (((kc * 4 + quad) ^ xo) * 8)];
#pragma unroll
            for (int mt = 0; mt < 4; mt++) {
                s16x8 af = *(const s16x8*)&As[(wm * 64 + mt * 16 + l16) * 64 +
                                              (((kc * 4 + quad) ^ xo) * 8)];
#pragma unroll
                for (int nt = 0; nt < 2; nt++)
                    acc[mt][nt] = MFMA16(af, bf[nt], acc[mt][nt]);
            }
        }
    }
#pragma unroll
    for (int mt = 0; mt < 4; mt++)
#pragma unroll
        for (int nt = 0; nt < 2; nt++)
#pragma unroll
            for (int r = 0; r < 4; r++) {
                int mg = m0 + wm * 64 + mt * 16 + quad * 4 + r;
                int ng = n0 + wn * 32 + nt * 16 + l16;
                C[(size_t)mg * 1024 + ng] = acc[mt][nt][r] + bias[ng];
            }
}

// ---------------------------------------------------------------------------
// Flash attention v6: transposed scores (K·Q^T), no-max exp2 softmax,
// DOUBLE-BUFFERED K/V LDS tiles with prefetch-after-barrier:
//   barrier publishes tile i -> immediately issue glds for tile i+1 into the
//   other buffer -> compute tile i. The next barrier's vmcnt(0) drain waits
//   only the residual latency after ~400 cycles of compute coverage.
// One barrier per iteration. 256 threads / 4 waves, 64 Q-rows, 64-key steps.
// grid: x = bh (XCD-pinned), y = q-block.
// ---------------------------------------------------------------------------
__global__ __launch_bounds__(256) void flash_attn(const unsigned short* __restrict__ Qr,
                                                  const unsigned short* __restrict__ Kr,
                                                  const unsigned short* __restrict__ Vt,
                                                  unsigned short* __restrict__ Cc) {
    __shared__ unsigned short Ks[2][64 * 64];    // [buf][key][d]     8 KB each
    __shared__ unsigned short Vs[2][64 * 64];    // [buf][e][s-rel]   8 KB each
    constexpr int LDT = 72;
    __shared__ unsigned short P4[4][16 * LDT];   // per-wave P^T: [q][key]  9 KB

    const int tid = threadIdx.x;
    const int lane = tid & 63, w = tid >> 6;
    const int l16 = lane & 15, quad = lane >> 4;
    const int bh = blockIdx.x, q0 = blockIdx.y * 64;
    const int b = bh >> 4, h = bh & 15;
    const int s_q = q0 + w * 16 + l16;           // this lane's q-row

    const unsigned short* Qp = Qr + ((size_t)(b * S_ + s_q)) * D_ + h * HD_;
    s16x8 aq0 = *(const s16x8*)&Qp[quad * 8];
    s16x8 aq1 = *(const s16x8*)&Qp[32 + quad * 8];

    const int srow = tid >> 3;
    const int sg = (tid & 7) ^ (srow & 7);
    const unsigned short* kg = Kr + ((size_t)(b * S_ + srow)) * D_ + h * HD_ + sg * 8;
    const unsigned short* vg = Vt + (((size_t)(b * H_ + h)) * HD_ + srow) * S_ + sg * 8;
    unsigned short* Kl0 = &Ks[0][tid * 8];
    unsigned short* Kl1 = &Ks[1][tid * 8];
    unsigned short* Vl0 = &Vs[0][tid * 8];
    unsigned short* Vl1 = &Vs[1][tid * 8];
    unsigned short* Pw = P4[w];
    const int pbase = l16 * LDT + quad * 4;      // P store base (per-lane)
    const int xo = l16 & 7;

    float l_part = 0.f;
    f32x4 o[4] = {};
    const f32x4 z4 = {0.f, 0.f, 0.f, 0.f};

    // prefetch tile 0 into buffer 0
    glds16(kg, Kl0);
    glds16(kg + (size_t)32 * D_, Kl0 + 2048);
    glds16(vg, Vl0);
    glds16(vg + (size_t)32 * S_, Vl0 + 2048);

    for (int k0 = 0; k0 < S_; k0 += 64) {
        const int cur = (k0 >> 6) & 1;
        __syncthreads();  // publishes tile cur (drains glds), and guards buf reuse
        if (k0 + 64 < S_) {
            // prefetch next tile into the other buffer; overlaps compute below
            const unsigned short* kn = kg + (size_t)(k0 + 64) * D_;
            const unsigned short* vn = vg + (k0 + 64);
            unsigned short* Kln = cur ? Kl0 : Kl1;
            unsigned short* Vln = cur ? Vl0 : Vl1;
            glds16(kn, Kln);
            glds16(kn + (size_t)32 * D_, Kln + 2048);
            glds16(vn, Vln);
            glds16(vn + (size_t)32 * S_, Vln + 2048);
        }
        const unsigned short* Ksc = Ks[cur];
        const unsigned short* Vsc = Vs[cur];

        // scores^T: D[key][q] = K·Q^T ; keys g*16+quad*4+r, col q=l16
#pragma unroll
        for (int g = 0; g < 4; g++) {
            int row = g * 16 + l16;
            s16x8 kb0 = *(const s16x8*)&Ksc[row * 64 + ((quad ^ xo) * 8)];
            s16x8 kb1 = *(const s16x8*)&Ksc[row * 64 + (((4 + quad) ^ xo) * 8)];
            f32x4 sc = MFMA16(kb0, aq0, z4);
            sc = MFMA16(kb1, aq1, sc);
            float e0 = exp2f(sc[0]), e1 = exp2f(sc[1]);
            float e2 = exp2f(sc[2]), e3 = exp2f(sc[3]);
            l_part += (e0 + e1) + (e2 + e3);
            u32x2 pv;
            pv[0] = pk_bf16(e0, e1);
            pv[1] = pk_bf16(e2, e3);
            *(u32x2*)&Pw[pbase + g * 16] = pv;   // 4 contig keys, 8B store
        }
        // P as B-operand for PV: B[k=key][n=q] = Pw[q=l16][key]
        s16x8 pB0 = *(const s16x8*)&Pw[l16 * LDT + quad * 8];
        s16x8 pB1 = *(const s16x8*)&Pw[l16 * LDT + 32 + quad * 8];
        // o^T[e][q] += V^T · P^T
#pragma unroll
        for (int t = 0; t < 4; t++) {
            int row = t * 16 + l16;
            s16x8 v0 = *(const s16x8*)&Vsc[row * 64 + ((quad ^ xo) * 8)];
            s16x8 v1 = *(const s16x8*)&Vsc[row * 64 + (((4 + quad) ^ xo) * 8)];
            o[t] = MFMA16(v0, pB0, o[t]);
            o[t] = MFMA16(v1, pB1, o[t]);
        }
    }
    float l = l_part;
    l += __shfl_xor(l, 16);
    l += __shfl_xor(l, 32);
    float rinv = 1.0f / l;
    unsigned short* Cp = Cc + ((size_t)(b * S_ + s_q)) * D_ + h * HD_;
#pragma unroll
    for (int t = 0; t < 4; t++) {
        u32x2 ov;
        ov[0] = pk_bf16(o[t][0] * rinv, o[t][1] * rinv);
        ov[1] = pk_bf16(o[t][2] * rinv, o[t][3] * rinv);
        *(u32x2*)&Cp[t * 16 + quad * 4] = ov;
    }
}

// ---------------------------------------------------------------------------
extern "C" void kernel_launch(void* const* d_in, const int* in_sizes, int n_in,
                              void* d_out, int out_size, void* d_ws, size_t ws_size,
                              hipStream_t stream) {
    const float* K_in = (const float*)d_in[0];
    const float* V_in = (const float*)d_in[1];
    const float* Q_in = (const float*)d_in[2];
    const float* Wk   = (const float*)d_in[3];
    const float* bk   = (const float*)d_in[4];
    const float* Wq   = (const float*)d_in[5];
    const float* bq   = (const float*)d_in[6];
    const float* Wv   = (const float*)d_in[7];
    const float* bv   = (const float*)d_in[8];
    const float* Wp   = (const float*)d_in[9];
    const float* bp   = (const float*)d_in[10];

    unsigned short* ws16 = (unsigned short*)d_ws;
    const size_t MC = 1u << 20;
    unsigned short* Qc  = ws16;            // 4M bf16 [B,S,D]
    unsigned short* Kc  = Qc + 4 * MC;
    unsigned short* Vc  = Kc + 4 * MC;
    unsigned short* Wt3 = Vc + 4 * MC;     // 3M
    unsigned short* Qr  = Wt3 + 3 * MC;    // 4M [B,S,D] projected, pre-scaled
    unsigned short* Kr  = Qr + 4 * MC;     // 4M [B,S,D]
    unsigned short* Vt  = Kr + 4 * MC;     // 4M [B,H,HD,S]
    unsigned short* Cc  = Qc;              // alias: Qc dead after gemm_qkv
    unsigned short* Wpb = Wt3;             // alias: Wt3 dead after gemm_qkv

    conv3<<<dim3(2048, 1, 3), 256, 0, stream>>>(Q_in, K_in, V_in, Qc, Kc, Vc);
    transpose_w3<<<dim3(64, 1, 3), 256, 0, stream>>>(Wq, Wk, Wv, Wt3);

    gemm_qkv<<<dim3(8, 32, 3), 256, 0, stream>>>(Qc, Kc, Vc, Wt3, bq, bk, bv, Qr, Kr, Vt);

    conv_bf16<<<512, 256, 0, stream>>>(Wp, Wpb);

    flash_attn<<<dim3(32, 32), 256, 0, stream>>>(Qr, Kr, Vt, Cc);

    gemm_out<<<dim3(16, 32), 256, 0, stream>>>(Cc, Wpb, bp, (float*)d_out);
}

// Round 8
// 262.252 us; speedup vs baseline: 1.0057x; 1.0057x over previous
//
#include <hip/hip_runtime.h>
#include <hip/hip_bf16.h>
#include <math.h>

typedef float f32x4 __attribute__((ext_vector_type(4)));
typedef short s16x8 __attribute__((ext_vector_type(8)));
typedef unsigned short us16x4 __attribute__((ext_vector_type(4)));
typedef unsigned short us16x8 __attribute__((ext_vector_type(8)));
typedef unsigned int u32x2 __attribute__((ext_vector_type(2)));

#define MFMA16(a, b, c) __builtin_amdgcn_mfma_f32_16x16x32_bf16(a, b, c, 0, 0, 0)

static constexpr int B_ = 2, S_ = 2048, D_ = 1024, H_ = 16, HD_ = 64;
// Q pre-scale: HD^-0.5 * log2(e)  -> flash softmax in exp2 domain, no max needed
static constexpr float QSCALE = 0.125f * 1.44269504088896340736f;

__device__ __forceinline__ unsigned short f2bf(float f) {
    unsigned int u = __builtin_bit_cast(unsigned int, f);
    u += 0x7fffu + ((u >> 16) & 1);  // round-to-nearest-even
    return (unsigned short)(u >> 16);
}

#if defined(__has_builtin) && __has_builtin(__builtin_amdgcn_cvt_pk_bf16_f32)
typedef __bf16 bf16x2v __attribute__((ext_vector_type(2)));
__device__ __forceinline__ unsigned int pk_bf16(float a, float b) {
    return __builtin_bit_cast(unsigned int, __builtin_amdgcn_cvt_pk_bf16_f32(a, b));
}
#else
__device__ __forceinline__ unsigned int pk_bf16(float a, float b) {
    return ((unsigned int)f2bf(a)) | (((unsigned int)f2bf(b)) << 16);
}
#endif

#if defined(__has_builtin) && __has_builtin(__builtin_amdgcn_exp2f)
__device__ __forceinline__ float fast_exp2(float x) { return __builtin_amdgcn_exp2f(x); }
#else
__device__ __forceinline__ float fast_exp2(float x) { return exp2f(x); }
#endif

__device__ __forceinline__ void glds16(const unsigned short* g, unsigned short* l) {
    __builtin_amdgcn_global_load_lds(
        (const __attribute__((address_space(1))) void*)g,
        (__attribute__((address_space(3))) void*)l, 16, 0, 0);
}

// ---------------------------------------------------------------------------
// fp32 -> bf16 flat converts
// ---------------------------------------------------------------------------
__global__ __launch_bounds__(256) void conv3(const float* __restrict__ s0,
                                             const float* __restrict__ s1,
                                             const float* __restrict__ s2,
                                             unsigned short* __restrict__ d0,
                                             unsigned short* __restrict__ d1,
                                             unsigned short* __restrict__ d2) {
    const int z = blockIdx.z;
    const float* src = (z == 0) ? s0 : (z == 1) ? s1 : s2;
    unsigned short* dst = (z == 0) ? d0 : (z == 1) ? d1 : d2;
    int i = (blockIdx.x * 256 + threadIdx.x) * 8;
    f32x4 a = *(const f32x4*)&src[i];
    f32x4 b = *(const f32x4*)&src[i + 4];
    s16x8 o;
#pragma unroll
    for (int j = 0; j < 4; j++) { o[j] = (short)f2bf(a[j]); o[4 + j] = (short)f2bf(b[j]); }
    *(s16x8*)&dst[i] = o;
}

__global__ __launch_bounds__(256) void conv_bf16(const float* __restrict__ src,
                                                 unsigned short* __restrict__ dst) {
    int i = (blockIdx.x * 256 + threadIdx.x) * 8;
    f32x4 a = *(const f32x4*)&src[i];
    f32x4 b = *(const f32x4*)&src[i + 4];
    s16x8 o;
#pragma unroll
    for (int j = 0; j < 4; j++) { o[j] = (short)f2bf(a[j]); o[4 + j] = (short)f2bf(b[j]); }
    *(s16x8*)&dst[i] = o;
}

// ---------------------------------------------------------------------------
// Weight transpose: Wt[(h*64+e)*1024 + d] = W[h*65536 + d*64 + e]
// ---------------------------------------------------------------------------
__global__ __launch_bounds__(256) void transpose_w3(const float* __restrict__ W0,
                                                    const float* __restrict__ W1,
                                                    const float* __restrict__ W2,
                                                    unsigned short* __restrict__ Wt3) {
    const int z = blockIdx.z;
    const float* W = (z == 0) ? W0 : (z == 1) ? W1 : W2;
    unsigned short* dst = Wt3 + ((size_t)z << 20);
    const int h = blockIdx.x >> 2, dg = blockIdx.x & 3;
    const int lane = threadIdx.x & 63, w = threadIdx.x >> 6;
    const float* Wh = W + ((size_t)h << 16);
#pragma unroll
    for (int it = 0; it < 8; it++) {
        int d0 = dg * 256 + it * 32 + w * 8;
        us16x8 o;
#pragma unroll
        for (int j = 0; j < 8; j++) o[j] = f2bf(Wh[(d0 + j) * 64 + lane]);
        *(us16x8*)&dst[(size_t)(h * 64 + lane) * 1024 + d0] = o;
    }
}

// ---------------------------------------------------------------------------
// 128x64-tile bf16 GEMM core, K=1024, BK=64, DOUBLE-BUFFERED glds staging
// with prefetch-after-barrier (one barrier/iter). LDS layout (ushorts):
//   [0..8192)     As buf0   [8192..12288)  Bs buf0
//   [12288..20480) As buf1  [20480..24576) Bs buf1      total 48 KB
// Occupancy: 3 blocks/CU (160/48) — same residency as the single-buffer
// version had at these grids, so the prefetch ILP is free.
// 4 waves: wave (wm=w&1, wn=w>>1) computes 64x32 as 4x2 16x16 MFMA tiles.
// ---------------------------------------------------------------------------
__device__ __forceinline__ void gemm_core_db(const unsigned short* __restrict__ A,
                                             const unsigned short* __restrict__ Bt,
                                             unsigned short* lds,
                                             int m0, int n0, f32x4 acc[4][2]) {
    const int tid = threadIdx.x;
    const int lane = tid & 63;
    const int w = tid >> 6, wm = w & 1, wn = w >> 1;
    const int l16 = lane & 15, quad = lane >> 4;
    const int srow = tid >> 3;
    const int sg = (tid & 7) ^ (srow & 7);
    const unsigned short* Ag = A + (size_t)(m0 + srow) * 1024 + sg * 8;
    const unsigned short* Bg = Bt + (size_t)(n0 + srow) * 1024 + sg * 8;
    const int xo = l16 & 7;
    unsigned short* AsBuf[2] = { lds, lds + 12288 };
    unsigned short* BsBuf[2] = { lds + 8192, lds + 20480 };

    // prefetch tile 0 -> buf 0
#pragma unroll
    for (int c = 0; c < 4; c++) glds16(Ag + (size_t)c * 32 * 1024, AsBuf[0] + tid * 8 + c * 2048);
#pragma unroll
    for (int c = 0; c < 2; c++) glds16(Bg + (size_t)c * 32 * 1024, BsBuf[0] + tid * 8 + c * 2048);

    for (int k0 = 0; k0 < 1024; k0 += 64) {
        const int cur = (k0 >> 6) & 1;
        __syncthreads();  // drains glds -> publishes buf cur; guards buf reuse
        if (k0 + 64 < 1024) {
            const int nxt = cur ^ 1;
#pragma unroll
            for (int c = 0; c < 4; c++)
                glds16(Ag + (size_t)c * 32 * 1024 + k0 + 64, AsBuf[nxt] + tid * 8 + c * 2048);
#pragma unroll
            for (int c = 0; c < 2; c++)
                glds16(Bg + (size_t)c * 32 * 1024 + k0 + 64, BsBuf[nxt] + tid * 8 + c * 2048);
        }
        const unsigned short* Asc = AsBuf[cur];
        const unsigned short* Bsc = BsBuf[cur];
#pragma unroll
        for (int kc = 0; kc < 2; kc++) {
            s16x8 bf[2];
#pragma unroll
            for (int nt = 0; nt < 2; nt++)
                bf[nt] = *(const s16x8*)&Bsc[(wn * 32 + nt * 16 + l16) * 64 +
                                             (((kc * 4 + quad) ^ xo) * 8)];
#pragma unroll
            for (int mt = 0; mt < 4; mt++) {
                s16x8 af = *(const s16x8*)&Asc[(wm * 64 + mt * 16 + l16) * 64 +
                                               (((kc * 4 + quad) ^ xo) * 8)];
#pragma unroll
                for (int nt = 0; nt < 2; nt++)
                    acc[mt][nt] = MFMA16(af, bf[nt], acc[mt][nt]);
            }
        }
    }
}

// QKV fused via grid.z: z=0 Q -> row-major [B,S,D] (pre-scaled), z=1 K -> row-major,
// z=2 V -> transposed [B,H,HD,S]. Epilogue: per-wave padded LDS transpose
// (reuses buf0 region — safe: last K-iter computes from buf1 only; per-wave
// private T, same-wave RAW ordered by lgkmcnt).
__global__ __launch_bounds__(256) void gemm_qkv(const unsigned short* __restrict__ Qc,
                                                const unsigned short* __restrict__ Kc,
                                                const unsigned short* __restrict__ Vc,
                                                const unsigned short* __restrict__ Wt3,
                                                const float* __restrict__ bq,
                                                const float* __restrict__ bk,
                                                const float* __restrict__ bv,
                                                unsigned short* __restrict__ Qr,
                                                unsigned short* __restrict__ Kr,
                                                unsigned short* __restrict__ Vt) {
    __shared__ unsigned short lds[24576];
    const int z = blockIdx.z;
    const unsigned short* A = (z == 0) ? Qc : (z == 1) ? Kc : Vc;
    const unsigned short* Bt = Wt3 + ((size_t)z << 20);
    const float* bias = (z == 0) ? bq : (z == 1) ? bk : bv;
    const int m0 = blockIdx.y * 128, n0 = blockIdx.x * 64;

    f32x4 acc[4][2] = {};
    gemm_core_db(A, Bt, lds, m0, n0, acc);

    const int tid = threadIdx.x;
    const int lane = tid & 63, w = tid >> 6;
    const int wm = w & 1, wn = w >> 1;
    const int l16 = lane & 15, quad = lane >> 4;
    const float scl = (z == 0) ? QSCALE : 1.0f;
    unsigned short* T = lds + w * 2560;  // per-wave; fits in [0..10240) = buf0 region

    if (z == 2) {
        // T: [n-local 32][72] (64 m-cols + 8 pad)
#pragma unroll
        for (int mt = 0; mt < 4; mt++)
#pragma unroll
            for (int nt = 0; nt < 2; nt++) {
                int nl = nt * 16 + l16;
                float bsv = bias[n0 + wn * 32 + nl];
#pragma unroll
                for (int r = 0; r < 4; r++) {
                    int ml = mt * 16 + quad * 4 + r;
                    T[nl * 72 + ml] = f2bf(acc[mt][nt][r] + bsv);
                }
            }
#pragma unroll
        for (int it = 0; it < 4; it++) {
            int rr = it * 8 + (lane >> 3);   // 0..31 n-local
            int g = lane & 7;                // m granule
            us16x8 vv = *(const us16x8*)&T[rr * 72 + g * 8];
            int n = n0 + wn * 32 + rr;       // h*64+e
            int mb = m0 + wm * 64 + g * 8;
            int b = mb >> 11, s = mb & 2047;
            *(us16x8*)&Vt[(((size_t)(b * H_ + (n >> 6))) * HD_ + (n & 63)) * S_ + s] = vv;
        }
    } else {
        // T: [m-local 64][40] (32 n-cols + 8 pad)
#pragma unroll
        for (int mt = 0; mt < 4; mt++)
#pragma unroll
            for (int nt = 0; nt < 2; nt++) {
                int nl = nt * 16 + l16;
                float bsv = bias[n0 + wn * 32 + nl];
#pragma unroll
                for (int r = 0; r < 4; r++) {
                    int ml = mt * 16 + quad * 4 + r;
                    T[ml * 40 + nl] = f2bf((acc[mt][nt][r] + bsv) * scl);
                }
            }
        unsigned short* dst = z ? Kr : Qr;
#pragma unroll
        for (int it = 0; it < 4; it++) {
            int rr = it * 16 + (lane >> 2);  // 0..63 m-local
            int g = lane & 3;                // n granule
            us16x8 vv = *(const us16x8*)&T[rr * 40 + g * 8];
            *(us16x8*)&dst[(size_t)(m0 + wm * 64 + rr) * 1024 + n0 + wn * 32 + g * 8] = vv;
        }
    }
}

// Final: C_f32[4096][1024] = Cc * Wp^T + bp  (same dbuf core)
__global__ __launch_bounds__(256) void gemm_out(const unsigned short* __restrict__ A,
                                                const unsigned short* __restrict__ Bt,
                                                const float* __restrict__ bias,
                                                float* __restrict__ C) {
    __shared__ unsigned short lds[24576];
    const int m0 = blockIdx.y * 128, n0 = blockIdx.x * 64;
    f32x4 acc[4][2] = {};
    gemm_core_db(A, Bt, lds, m0, n0, acc);
    const int lane = threadIdx.x & 63, w = threadIdx.x >> 6;
    const int wm = w & 1, wn = w >> 1;
    const int l16 = lane & 15, quad = lane >> 4;
#pragma unroll
    for (int mt = 0; mt < 4; mt++)
#pragma unroll
        for (int nt = 0; nt < 2; nt++)
#pragma unroll
            for (int r = 0; r < 4; r++) {
                int mg = m0 + wm * 64 + mt * 16 + quad * 4 + r;
                int ng = n0 + wn * 32 + nt * 16 + l16;
                C[(size_t)mg * 1024 + ng] = acc[mt][nt][r] + bias[ng];
            }
}

// ---------------------------------------------------------------------------
// Flash attention (round-6 version, known 85.6 µs): transposed scores (K·Q^T),
// no-max exp2 softmax, packed bf16, single-buffered shared K/V tiles.
// 256 threads / 4 waves, 64 Q-rows, 64-key steps. grid: x = bh, y = q-block.
// ---------------------------------------------------------------------------
__global__ __launch_bounds__(256) void flash_attn(const unsigned short* __restrict__ Qr,
                                                  const unsigned short* __restrict__ Kr,
                                                  const unsigned short* __restrict__ Vt,
                                                  unsigned short* __restrict__ Cc) {
    __shared__ unsigned short Ks[64 * 64];       // [key][d]
    __shared__ unsigned short Vs[64 * 64];       // [e][s-rel]
    constexpr int LDT = 72;
    __shared__ unsigned short P4[4][16 * LDT];   // per-wave P^T: [q][key]

    const int tid = threadIdx.x;
    const int lane = tid & 63, w = tid >> 6;
    const int l16 = lane & 15, quad = lane >> 4;
    const int bh = blockIdx.x, q0 = blockIdx.y * 64;
    const int b = bh >> 4, h = bh & 15;
    const int s_q = q0 + w * 16 + l16;

    const unsigned short* Qp = Qr + ((size_t)(b * S_ + s_q)) * D_ + h * HD_;
    s16x8 aq0 = *(const s16x8*)&Qp[quad * 8];
    s16x8 aq1 = *(const s16x8*)&Qp[32 + quad * 8];

    const int srow = tid >> 3;
    const int sg = (tid & 7) ^ (srow & 7);
    const unsigned short* kg = Kr + ((size_t)(b * S_ + srow)) * D_ + h * HD_ + sg * 8;
    const unsigned short* vg = Vt + (((size_t)(b * H_ + h)) * HD_ + srow) * S_ + sg * 8;
    unsigned short* Kl = Ks + tid * 8;
    unsigned short* Vl = Vs + tid * 8;
    unsigned short* Pw = P4[w];
    const int pbase = l16 * LDT + quad * 4;
    const int xo = l16 & 7;

    float l_part = 0.f;
    f32x4 o[4] = {};
    const f32x4 z4 = {0.f, 0.f, 0.f, 0.f};

    for (int k0 = 0; k0 < S_; k0 += 64) {
        __syncthreads();
        glds16(kg, Kl);
        glds16(kg + (size_t)32 * D_, Kl + 2048);
        glds16(vg, Vl);
        glds16(vg + (size_t)32 * S_, Vl + 2048);
        kg += (size_t)64 * D_;
        vg += 64;
        __syncthreads();

#pragma unroll
        for (int g = 0; g < 4; g++) {
            int row = g * 16 + l16;
            s16x8 kb0 = *(const s16x8*)&Ks[row * 64 + ((quad ^ xo) * 8)];
            s16x8 kb1 = *(const s16x8*)&Ks[row * 64 + (((4 + quad) ^ xo) * 8)];
            f32x4 sc = MFMA16(kb0, aq0, z4);
            sc = MFMA16(kb1, aq1, sc);
            float e0 = fast_exp2(sc[0]), e1 = fast_exp2(sc[1]);
            float e2 = fast_exp2(sc[2]), e3 = fast_exp2(sc[3]);
            l_part += (e0 + e1) + (e2 + e3);
            u32x2 pv;
            pv[0] = pk_bf16(e0, e1);
            pv[1] = pk_bf16(e2, e3);
            *(u32x2*)&Pw[pbase + g * 16] = pv;
        }
        s16x8 pB0 = *(const s16x8*)&Pw[l16 * LDT + quad * 8];
        s16x8 pB1 = *(const s16x8*)&Pw[l16 * LDT + 32 + quad * 8];
#pragma unroll
        for (int t = 0; t < 4; t++) {
            int row = t * 16 + l16;
            s16x8 v0 = *(const s16x8*)&Vs[row * 64 + ((quad ^ xo) * 8)];
            s16x8 v1 = *(const s16x8*)&Vs[row * 64 + (((4 + quad) ^ xo) * 8)];
            o[t] = MFMA16(v0, pB0, o[t]);
            o[t] = MFMA16(v1, pB1, o[t]);
        }
    }
    float l = l_part;
    l += __shfl_xor(l, 16);
    l += __shfl_xor(l, 32);
    float rinv = 1.0f / l;
    unsigned short* Cp = Cc + ((size_t)(b * S_ + s_q)) * D_ + h * HD_;
#pragma unroll
    for (int t = 0; t < 4; t++) {
        u32x2 ov;
        ov[0] = pk_bf16(o[t][0] * rinv, o[t][1] * rinv);
        ov[1] = pk_bf16(o[t][2] * rinv, o[t][3] * rinv);
        *(u32x2*)&Cp[t * 16 + quad * 4] = ov;
    }
}

// ---------------------------------------------------------------------------
extern "C" void kernel_launch(void* const* d_in, const int* in_sizes, int n_in,
                              void* d_out, int out_size, void* d_ws, size_t ws_size,
                              hipStream_t stream) {
    const float* K_in = (const float*)d_in[0];
    const float* V_in = (const float*)d_in[1];
    const float* Q_in = (const float*)d_in[2];
    const float* Wk   = (const float*)d_in[3];
    const float* bk   = (const float*)d_in[4];
    const float* Wq   = (const float*)d_in[5];
    const float* bq   = (const float*)d_in[6];
    const float* Wv   = (const float*)d_in[7];
    const float* bv   = (const float*)d_in[8];
    const float* Wp   = (const float*)d_in[9];
    const float* bp   = (const float*)d_in[10];

    unsigned short* ws16 = (unsigned short*)d_ws;
    const size_t MC = 1u << 20;
    unsigned short* Qc  = ws16;            // 4M bf16 [B,S,D]
    unsigned short* Kc  = Qc + 4 * MC;
    unsigned short* Vc  = Kc + 4 * MC;
    unsigned short* Wt3 = Vc + 4 * MC;     // 3M
    unsigned short* Qr  = Wt3 + 3 * MC;    // 4M [B,S,D] projected, pre-scaled
    unsigned short* Kr  = Qr + 4 * MC;     // 4M [B,S,D]
    unsigned short* Vt  = Kr + 4 * MC;     // 4M [B,H,HD,S]
    unsigned short* Cc  = Qc;              // alias: Qc dead after gemm_qkv
    unsigned short* Wpb = Wt3;             // alias: Wt3 dead after gemm_qkv

    conv3<<<dim3(2048, 1, 3), 256, 0, stream>>>(Q_in, K_in, V_in, Qc, Kc, Vc);
    transpose_w3<<<dim3(64, 1, 3), 256, 0, stream>>>(Wq, Wk, Wv, Wt3);

    gemm_qkv<<<dim3(16, 32, 3), 256, 0, stream>>>(Qc, Kc, Vc, Wt3, bq, bk, bv, Qr, Kr, Vt);

    conv_bf16<<<512, 256, 0, stream>>>(Wp, Wpb);

    flash_attn<<<dim3(32, 32), 256, 0, stream>>>(Qr, Kr, Vt, Cc);

    gemm_out<<<dim3(16, 32), 256, 0, stream>>>(Cc, Wpb, bp, (float*)d_out);
}